// Round 9
// baseline (306.363 us; speedup 1.0000x reference)
//
#include <hip/hip_runtime.h>

// ProtoSAE fused: h = relu(BN(x@W1^T + b1)); enc = h@W2^T + b2; act = f(||enc-proto||^2)
// T=8192, NI=1024, L=128, H=128, P=64.
// R9: main loop LDS traffic halved: A (x) frags read DIRECT from global (L2-hot via
//     XCD chunking), ping-pong prefetched 1 K-step ahead in registers. B (W1) keeps
//     proven swizzled global_load_lds, double-buffered (32KB) with R8's
//     1-barrier-per-K-step sync. 48KB LDS -> 3 blocks/CU. Epilogue = R6/R8 verbatim.

#define NTOK 8192
#define NI   1024
#define NL   128
#define NH   128
#define NP   64

typedef __bf16 bf16x8 __attribute__((ext_vector_type(8)));
typedef float f32x4 __attribute__((ext_vector_type(4)));
typedef int   i32x4 __attribute__((ext_vector_type(4)));

static __device__ __forceinline__ unsigned short f2bf(float f) {
  union { float f; unsigned int u; } v; v.f = f;
  const unsigned int u = v.u;
  return (unsigned short)((u + 0x7fffu + ((u >> 16) & 1u)) >> 16);  // RNE
}

// W2 -> bf16 (8 elems/thread)
__global__ void cvt_f32_bf16(const float* __restrict__ in,
                             unsigned short* __restrict__ out, int n8) {
  const int i = blockIdx.x * blockDim.x + threadIdx.x;
  if (i >= n8) return;
  const float4* p = (const float4*)in;
  const float4 a = p[2 * i], b = p[2 * i + 1];
  unsigned short v[8] __attribute__((aligned(16))) = {
      f2bf(a.x), f2bf(a.y), f2bf(a.z), f2bf(a.w),
      f2bf(b.x), f2bf(b.y), f2bf(b.z), f2bf(b.w)};
  ((uint4*)out)[i] = *(const uint4*)v;
}

// per-row symmetric int8 quantization of x (rows<NTOK) and W1 (rest); 1 wave per row
__global__ void quant_rows_i8_dual(const float* __restrict__ x,
                                   const float* __restrict__ w1,
                                   signed char* __restrict__ xq,
                                   signed char* __restrict__ w1q,
                                   float* __restrict__ sx,
                                   float* __restrict__ sw) {
  const int row = blockIdx.x * 4 + (threadIdx.x >> 6);
  const int lane = threadIdx.x & 63;
  const float* src;
  unsigned int* dst;
  float* sp;
  if (row < NTOK) {
    src = x + (size_t)row * 1024;
    dst = (unsigned int*)(xq + (size_t)row * 1024);
    sp  = sx + row;
  } else {
    const int r = row - NTOK;
    src = w1 + (size_t)r * 1024;
    dst = (unsigned int*)(w1q + (size_t)r * 1024);
    sp  = sw + r;
  }
  const float4* s4 = (const float4*)src;
  float4 v[4];
  float m = 0.f;
#pragma unroll
  for (int j = 0; j < 4; ++j) {
    v[j] = s4[lane + 64 * j];
    m = fmaxf(m, fmaxf(fmaxf(fabsf(v[j].x), fabsf(v[j].y)),
                       fmaxf(fabsf(v[j].z), fabsf(v[j].w))));
  }
#pragma unroll
  for (int s = 1; s < 64; s <<= 1) m = fmaxf(m, __shfl_xor(m, s));
  m = fmaxf(m, 1e-20f);
  const float inv = 127.0f / m;
  if (lane == 0) *sp = m * (1.0f / 127.0f);
#pragma unroll
  for (int j = 0; j < 4; ++j) {
    const int a = (int)rintf(fminf(127.f, fmaxf(-127.f, v[j].x * inv)));
    const int b = (int)rintf(fminf(127.f, fmaxf(-127.f, v[j].y * inv)));
    const int c = (int)rintf(fminf(127.f, fmaxf(-127.f, v[j].z * inv)));
    const int d = (int)rintf(fminf(127.f, fmaxf(-127.f, v[j].w * inv)));
    dst[lane + 64 * j] = (unsigned)(a & 255) | ((unsigned)(b & 255) << 8) |
                         ((unsigned)(c & 255) << 16) | ((unsigned)(d & 255) << 24);
  }
}

static __device__ __forceinline__ void async16(const void* g, void* l) {
  __builtin_amdgcn_global_load_lds(
      (const __attribute__((address_space(1))) unsigned int*)g,
      (__attribute__((address_space(3))) unsigned int*)l, 16, 0, 0);
}

// Block: 128 tokens x 1 latent, 4 waves as 2x2 (token-half x hcol-half).
// LDS (48 KB): main loop B dbuf [0,16K)+[16K,32K) 128x128 i8 swz(r&7).
// Epilogue: hs bf16 [0,32K) swz(r&15); W2s [32K,48K) swz(r&15).
__global__ __launch_bounds__(256, 3) void proto_fused(
    const signed char* __restrict__ xq,       // [8192][1024] i8
    const signed char* __restrict__ w1q,      // [16384][1024] i8
    const unsigned short* __restrict__ w2b,   // [128][64][128] bf16
    const float* __restrict__ sx,             // [8192]
    const float* __restrict__ sw,             // [16384]
    const float* __restrict__ b1,
    const float* __restrict__ gamma, const float* __restrict__ beta,
    const float* __restrict__ rmean, const float* __restrict__ rvar,
    const float* __restrict__ b2,
    const float* __restrict__ protos,
    float* __restrict__ out)                  // [8192][128]
{
  __shared__ __attribute__((aligned(128))) char smem[49152];
  const int tid  = threadIdx.x;
  const int wave = tid >> 6;
  const int lane = tid & 63;
  const int l15  = lane & 15;
  const int l4   = lane >> 4;
  const int wr   = wave >> 1;
  const int wc   = wave & 1;

  // XCD-chunked swizzle (T1): id&7 = XCD; each XCD walks 8tt x 16lat chunks (~3MB L2 set)
  const int id    = blockIdx.x;
  const int xcd   = id & 7;
  const int local = id >> 3;
  const int chunk = local >> 7;
  const int wi    = local & 127;
  const int tt    = chunk * 8 + (wi & 7);
  const int lat   = xcd * 16 + (wi >> 3);
  const int t0    = tt * 128;

  const int srow  = lane >> 3;                    // row within 8-row staging chunk
  const int scolb = ((lane & 7) ^ srow) * 16;     // swizzled source byte offset

  // B staging bases (4 global_load_lds per wave per K-step)
  const signed char* bB[4];
#pragma unroll
  for (int j = 0; j < 4; ++j) {
    const int row = wave * 32 + j * 8 + srow;
    bB[j] = w1q + (size_t)(lat * NH + row) * NI + scolb;
  }

  // A global read bases: frag bytes = xq[(t0+wr*64+m*16+l15)*1024 + ks*128 + (kk*4+l4)*16]
  const signed char* xA[4];
#pragma unroll
  for (int m = 0; m < 4; ++m)
    xA[m] = xq + (size_t)(t0 + wr * 64 + m * 16 + l15) * NI + l4 * 16;

  i32x4 acc[4][4] = {};
  i32x4 aP[8], aQ[8];      // ping/pong A fragments, q = kk*4 + m

  auto stageB = [&](int ks, int buf) {
    const int k0 = ks * 128;
    const int bofs = buf * 16384;
#pragma unroll
    for (int j = 0; j < 4; ++j)
      async16(bB[j] + k0, smem + bofs + (wave * 4 + j) * 1024);
  };

  const int rx = l15 & 7;

#define LOADA(DST, KS)                                                     \
  _Pragma("unroll")                                                        \
  for (int q = 0; q < 8; ++q)                                              \
    DST[q] = *(const i32x4*)(xA[q & 3] + (KS) * 128 + (q >> 2) * 64);

#define BODY(AF, BUF)                                                      \
  {                                                                        \
    _Pragma("unroll")                                                      \
    for (int kk = 0; kk < 2; ++kk) {                                       \
      const int koff = ((kk * 4 + l4) ^ rx) << 4;                          \
      i32x4 b[4];                                                          \
      _Pragma("unroll")                                                    \
      for (int n = 0; n < 4; ++n)                                          \
        b[n] = *(const i32x4*)(smem + (BUF) * 16384 +                      \
                               (wc * 64 + n * 16 + l15) * 128 + koff);     \
      __builtin_amdgcn_s_setprio(1);                                       \
      _Pragma("unroll")                                                    \
      for (int m = 0; m < 4; ++m)                                          \
        _Pragma("unroll")                                                  \
        for (int n = 0; n < 4; ++n)                                        \
          acc[m][n] = __builtin_amdgcn_mfma_i32_16x16x64_i8(               \
              AF[kk * 4 + m], b[n], acc[m][n], 0, 0, 0);                   \
      __builtin_amdgcn_s_setprio(0);                                       \
    }                                                                      \
  }

  // ---- GEMM1: i8, BK=128, 8 K-steps; B dbuf 1-barrier/K-step; A reg-pingpong ----
  stageB(0, 0);
  LOADA(aP, 0);
  __syncthreads();                       // B(0) resident
#pragma unroll
  for (int ks = 0; ks < 8; ks += 2) {
    if (ks + 1 < 8) stageB(ks + 1, 1);   // issue next-tile loads FIRST
    LOADA(aQ, ks + 1);                   // ks+1 <= 7 always
    BODY(aP, 0);
    __syncthreads();                     // drain lands after ~650cyc MFMA; buf0 reads done
    if (ks + 2 < 8) {
      stageB(ks + 2, 0);
      LOADA(aP, ks + 2);
    }
    BODY(aQ, 1);
    __syncthreads();
  }
#undef LOADA
#undef BODY

  // ---- stage W2[lat] into [32K,48K): 64x128 bf16, swz(r&15) ----
#pragma unroll
  for (int i = 0; i < 4; ++i) {
    const int r = wave * 4 + i * 16 + l4;              // 0..63
    const int c = (lane & 15) ^ (r & 15);
    async16(w2b + (size_t)lat * NP * NH + r * NH + c * 8,
            smem + 32768 + (wave * 64 + i * 256) * 16);
  }

  // ---- epilogue 1: dequant + BN(eval) + ReLU -> hs bf16 [128][128] swz(r&15) ----
  float sxv[4][4];
#pragma unroll
  for (int m = 0; m < 4; ++m)
#pragma unroll
    for (int r = 0; r < 4; ++r)
      sxv[m][r] = sx[t0 + wr * 64 + m * 16 + l4 * 4 + r];

#pragma unroll
  for (int n = 0; n < 4; ++n) {
    const int hc = wc * 64 + n * 16 + l15;
    const int gi = lat * NH + hc;
    const float sc_ = gamma[gi] * rsqrtf(rvar[gi] + 1e-5f);
    const float Kc  = sw[gi] * sc_;
    const float Cc  = b1[gi] * sc_ + beta[gi] - rmean[gi] * sc_;
    const int cchunk = hc >> 3, cin = (hc & 7) * 2;
#pragma unroll
    for (int m = 0; m < 4; ++m)
#pragma unroll
      for (int r = 0; r < 4; ++r) {
        float v = fmaf((float)acc[m][n][r] * sxv[m][r], Kc, Cc);
        v = v > 0.f ? v : 0.f;
        const int row = wr * 64 + m * 16 + l4 * 4 + r;
        const int pbyte = row * 256 + ((cchunk ^ (l4 * 4 + r)) << 4) + cin;
        *(__bf16*)(smem + pbyte) = (__bf16)v;
      }
  }
  __syncthreads();   // drains W2 vmcnt + hs lgkm

  // ---- epilogue 2: enc = h @ W2^T (M=128, N=64, K=128), bf16, swizzled reads ----
  f32x4 acc2[2][4] = {};
#pragma unroll
  for (int kk = 0; kk < 4; ++kk) {
    const int pcsel = kk * 4 + l4;
    bf16x8 a2[2], bw[4];
#pragma unroll
    for (int m = 0; m < 2; ++m) {
      const int row = wave * 32 + m * 16 + l15;
      a2[m] = *(const bf16x8*)(smem + row * 256 + ((pcsel ^ l15) << 4));
    }
#pragma unroll
    for (int n = 0; n < 4; ++n) {
      const int rp = n * 16 + l15;
      bw[n] = *(const bf16x8*)(smem + 32768 + rp * 256 + ((pcsel ^ l15) << 4));
    }
#pragma unroll
    for (int m = 0; m < 2; ++m)
#pragma unroll
      for (int n = 0; n < 4; ++n)
        acc2[m][n] = __builtin_amdgcn_mfma_f32_16x16x32_bf16(a2[m], bw[n], acc2[m][n], 0, 0, 0);
  }

  // ---- epilogue 3: L2 distance + log2-based activation ----
  float pb[4], pp[4];
#pragma unroll
  for (int n = 0; n < 4; ++n) {
    const int p = n * 16 + l15;
    pb[n] = b2[lat * NP + p];
    pp[n] = protos[lat * NP + p];
  }
  const float scale2 = 0.69314718056f * 300.0f / logf(10000.0f);
#pragma unroll
  for (int m = 0; m < 2; ++m)
#pragma unroll
    for (int r = 0; r < 4; ++r) {
      float s = 0.f;
#pragma unroll
      for (int n = 0; n < 4; ++n) {
        const float e = acc2[m][n][r] + pb[n] - pp[n];
        s += e * e;
      }
      s += __shfl_xor(s, 1);
      s += __shfl_xor(s, 2);
      s += __shfl_xor(s, 4);
      s += __shfl_xor(s, 8);
      if (l15 == 0) {
        const float a = (__log2f(s + 1.0f) - __log2f(s + 1e-4f)) * scale2 - 100.0f;
        const int trow = wave * 32 + m * 16 + l4 * 4 + r;
        out[(size_t)(t0 + trow) * NL + lat] = a;
      }
    }
}

extern "C" void kernel_launch(void* const* d_in, const int* in_sizes, int n_in,
                              void* d_out, int out_size, void* d_ws, size_t ws_size,
                              hipStream_t stream) {
  const float* x      = (const float*)d_in[0];
  const float* W1     = (const float*)d_in[1];
  const float* b1     = (const float*)d_in[2];
  const float* gamma  = (const float*)d_in[3];
  const float* beta   = (const float*)d_in[4];
  const float* rmean  = (const float*)d_in[5];
  const float* rvar   = (const float*)d_in[6];
  const float* W2     = (const float*)d_in[7];
  const float* b2     = (const float*)d_in[8];
  const float* protos = (const float*)d_in[9];
  float* out = (float*)d_out;

  // workspace: xq 8MB | w1q 16MB | w2b 2MB | sx 32KB | sw 64KB
  char* ws = (char*)d_ws;
  signed char*    xq  = (signed char*)ws;
  signed char*    w1q = (signed char*)(ws + (size_t)8 * 1024 * 1024);
  unsigned short* w2b = (unsigned short*)(ws + (size_t)24 * 1024 * 1024);
  float*          sx  = (float*)(ws + (size_t)26 * 1024 * 1024);
  float*          sw  = (float*)(ws + (size_t)26 * 1024 * 1024 + 64 * 1024);

  quant_rows_i8_dual<<<(NTOK + NL * NH) / 4, 256, 0, stream>>>(x, W1, xq, w1q, sx, sw);
  {
    const int n8w2 = NL * NP * NH / 8;
    cvt_f32_bf16<<<(n8w2 + 255) / 256, 256, 0, stream>>>(W2, w2b, n8w2);
  }

  proto_fused<<<dim3(8192), 256, 0, stream>>>(xq, w1q, w2b, sx, sw, b1, gamma, beta,
                                              rmean, rvar, b2, protos, out);
}

// Round 10
// 223.163 us; speedup vs baseline: 1.3728x; 1.3728x over previous
//
#include <hip/hip_runtime.h>

// ProtoSAE fused: h = relu(BN(x@W1^T + b1)); enc = h@W2^T + b2; act = f(||enc-proto||^2)
// T=8192, NI=1024, L=128, H=128, P=64.
// R10: R6 geometry restored (128x128 tile, 4 waves, 48KB, 3 blocks/CU, 2-barrier
//      K-loop). GEMM1 MFMA switched 16x16x64 -> 32x32x32 i8 (4404 vs 3944 TOPS,
//      half the MFMA instructions, same ds_read count/pattern). Epilogue remapped
//      for 32x32 C/D layout; GEMM2 + activation unchanged.

#define NTOK 8192
#define NI   1024
#define NL   128
#define NH   128
#define NP   64

typedef __bf16 bf16x8 __attribute__((ext_vector_type(8)));
typedef float f32x4 __attribute__((ext_vector_type(4)));
typedef int   i32x4 __attribute__((ext_vector_type(4)));
typedef int   i32x16 __attribute__((ext_vector_type(16)));

static __device__ __forceinline__ unsigned short f2bf(float f) {
  union { float f; unsigned int u; } v; v.f = f;
  const unsigned int u = v.u;
  return (unsigned short)((u + 0x7fffu + ((u >> 16) & 1u)) >> 16);  // RNE
}

// W2 -> bf16 (8 elems/thread)
__global__ void cvt_f32_bf16(const float* __restrict__ in,
                             unsigned short* __restrict__ out, int n8) {
  const int i = blockIdx.x * blockDim.x + threadIdx.x;
  if (i >= n8) return;
  const float4* p = (const float4*)in;
  const float4 a = p[2 * i], b = p[2 * i + 1];
  unsigned short v[8] __attribute__((aligned(16))) = {
      f2bf(a.x), f2bf(a.y), f2bf(a.z), f2bf(a.w),
      f2bf(b.x), f2bf(b.y), f2bf(b.z), f2bf(b.w)};
  ((uint4*)out)[i] = *(const uint4*)v;
}

// per-row symmetric int8 quantization of x (rows<NTOK) and W1 (rest); 1 wave per row
__global__ void quant_rows_i8_dual(const float* __restrict__ x,
                                   const float* __restrict__ w1,
                                   signed char* __restrict__ xq,
                                   signed char* __restrict__ w1q,
                                   float* __restrict__ sx,
                                   float* __restrict__ sw) {
  const int row = blockIdx.x * 4 + (threadIdx.x >> 6);
  const int lane = threadIdx.x & 63;
  const float* src;
  unsigned int* dst;
  float* sp;
  if (row < NTOK) {
    src = x + (size_t)row * 1024;
    dst = (unsigned int*)(xq + (size_t)row * 1024);
    sp  = sx + row;
  } else {
    const int r = row - NTOK;
    src = w1 + (size_t)r * 1024;
    dst = (unsigned int*)(w1q + (size_t)r * 1024);
    sp  = sw + r;
  }
  const float4* s4 = (const float4*)src;
  float4 v[4];
  float m = 0.f;
#pragma unroll
  for (int j = 0; j < 4; ++j) {
    v[j] = s4[lane + 64 * j];
    m = fmaxf(m, fmaxf(fmaxf(fabsf(v[j].x), fabsf(v[j].y)),
                       fmaxf(fabsf(v[j].z), fabsf(v[j].w))));
  }
#pragma unroll
  for (int s = 1; s < 64; s <<= 1) m = fmaxf(m, __shfl_xor(m, s));
  m = fmaxf(m, 1e-20f);
  const float inv = 127.0f / m;
  if (lane == 0) *sp = m * (1.0f / 127.0f);
#pragma unroll
  for (int j = 0; j < 4; ++j) {
    const int a = (int)rintf(fminf(127.f, fmaxf(-127.f, v[j].x * inv)));
    const int b = (int)rintf(fminf(127.f, fmaxf(-127.f, v[j].y * inv)));
    const int c = (int)rintf(fminf(127.f, fmaxf(-127.f, v[j].z * inv)));
    const int d = (int)rintf(fminf(127.f, fmaxf(-127.f, v[j].w * inv)));
    dst[lane + 64 * j] = (unsigned)(a & 255) | ((unsigned)(b & 255) << 8) |
                         ((unsigned)(c & 255) << 16) | ((unsigned)(d & 255) << 24);
  }
}

static __device__ __forceinline__ void async16(const void* g, void* l) {
  __builtin_amdgcn_global_load_lds(
      (const __attribute__((address_space(1))) unsigned int*)g,
      (__attribute__((address_space(3))) unsigned int*)l, 16, 0, 0);
}

// Block: 128 tokens x 1 latent, 4 waves as 2x2 (token-half x hcol-half).
// LDS: A [0,16K) 128x128 i8 swz(r&7); B [16K,32K) same; W2s [32K,48K) 64x128 bf16
//      swz(r&15) persistent; epilogue hs [0,32K) 128x128 bf16 swz(r&15).
__global__ __launch_bounds__(256, 3) void proto_fused(
    const signed char* __restrict__ xq,       // [8192][1024] i8
    const signed char* __restrict__ w1q,      // [16384][1024] i8
    const unsigned short* __restrict__ w2b,   // [128][64][128] bf16
    const float* __restrict__ sx,             // [8192]
    const float* __restrict__ sw,             // [16384]
    const float* __restrict__ b1,
    const float* __restrict__ gamma, const float* __restrict__ beta,
    const float* __restrict__ rmean, const float* __restrict__ rvar,
    const float* __restrict__ b2,
    const float* __restrict__ protos,
    float* __restrict__ out)                  // [8192][128]
{
  __shared__ __attribute__((aligned(128))) char smem[49152];
  const int tid  = threadIdx.x;
  const int wave = tid >> 6;
  const int lane = tid & 63;
  const int l15  = lane & 15;
  const int l4   = lane >> 4;
  const int l31  = lane & 31;
  const int l5   = lane >> 5;
  const int wr   = wave >> 1;
  const int wc   = wave & 1;
  const int t0   = blockIdx.x * 128;
  const int lat  = blockIdx.y;

  const int srow  = lane >> 3;                    // row within 8-row staging chunk
  const int scolb = ((lane & 7) ^ srow) * 16;     // swizzled source byte offset

  i32x16 acc[2][2] = {};   // 2x2 frags of 32x32; C/D: col=l31, row=(r&3)+8*(r>>2)+4*l5

  // ---- stage W2[lat] once: 64x128 bf16 -> smem+32768, chunk ^= row&15 swizzle ----
#pragma unroll
  for (int i = 0; i < 4; ++i) {
    const int r = wave * 4 + i * 16 + l4;              // 0..63
    const int c = (lane & 15) ^ (r & 15);
    async16(w2b + (size_t)lat * NP * NH + r * NH + c * 8,
            smem + 32768 + (wave * 64 + i * 256) * 16);
  }

  auto stage = [&](int ks) {
    const int k0 = ks * 128;
#pragma unroll
    for (int j = 0; j < 4; ++j) {
      const int row = wave * 32 + j * 8 + srow;
      async16(xq + (size_t)(t0 + row) * NI + k0 + scolb,
              smem + (wave * 4 + j) * 1024);
      async16(w1q + (size_t)(lat * NH + row) * NI + k0 + scolb,
              smem + 16384 + (wave * 4 + j) * 1024);
    }
  };

  // ---- GEMM1 main loop: i8 32x32x32, BK=128, 8 K-steps (m97 structure) ----
  // A-frag (mi): row = wr*64 + mi*32 + l31, 16B K-chunk index = kv*2 + l5 (logical),
  // physical chunk = logical ^ (row&7); row&7 == l31&7.
  stage(0);
  const int rx = l31 & 7;
  const int rbA0 = (wr * 64 + l31) * 128;
  const int rbB0 = 16384 + (wc * 64 + l31) * 128;
  for (int ks = 0; ks < 8; ++ks) {
    __syncthreads();
#pragma unroll
    for (int kv = 0; kv < 4; ++kv) {
      const int koff = ((kv * 2 + l5) ^ rx) << 4;
      i32x4 a[2], b[2];
#pragma unroll
      for (int mi = 0; mi < 2; ++mi)
        a[mi] = *(const i32x4*)(smem + rbA0 + mi * 32 * 128 + koff);
#pragma unroll
      for (int ni = 0; ni < 2; ++ni)
        b[ni] = *(const i32x4*)(smem + rbB0 + ni * 32 * 128 + koff);
#pragma unroll
      for (int mi = 0; mi < 2; ++mi)
#pragma unroll
        for (int ni = 0; ni < 2; ++ni)
          acc[mi][ni] = __builtin_amdgcn_mfma_i32_32x32x32_i8(a[mi], b[ni], acc[mi][ni], 0, 0, 0);
    }
    __syncthreads();
    if (ks + 1 < 8) stage(ks + 1);
  }

  // ---- epilogue 1: dequant + BN(eval) + ReLU -> hs bf16 [128][128] swz(r&15) ----
  // 32x32 C/D: value acc[mi][ni][r] -> row = wr*64+mi*32+(r&3)+8*(r>>2)+4*l5,
  //                                    col = wc*64+ni*32+l31
  float sxv[2][16];
#pragma unroll
  for (int mi = 0; mi < 2; ++mi)
#pragma unroll
    for (int r = 0; r < 16; ++r)
      sxv[mi][r] = sx[t0 + wr * 64 + mi * 32 + (r & 3) + 8 * (r >> 2) + 4 * l5];

#pragma unroll
  for (int ni = 0; ni < 2; ++ni) {
    const int hc = wc * 64 + ni * 32 + l31;
    const int gi = lat * NH + hc;
    const float sc_ = gamma[gi] * rsqrtf(rvar[gi] + 1e-5f);
    const float Kc  = sw[gi] * sc_;
    const float Cc  = b1[gi] * sc_ + beta[gi] - rmean[gi] * sc_;
    const int cchunk = hc >> 3, cin = (hc & 7) * 2;
#pragma unroll
    for (int mi = 0; mi < 2; ++mi)
#pragma unroll
      for (int r = 0; r < 16; ++r) {
        float v = fmaf((float)acc[mi][ni][r] * sxv[mi][r], Kc, Cc);
        v = v > 0.f ? v : 0.f;
        const int row = wr * 64 + mi * 32 + (r & 3) + 8 * (r >> 2) + 4 * l5;
        const int pbyte = row * 256 + ((cchunk ^ (row & 15)) << 4) + cin;
        *(__bf16*)(smem + pbyte) = (__bf16)v;
      }
  }
  __syncthreads();

  // ---- epilogue 2: enc = h @ W2^T (M=128, N=64, K=128), bf16 16x16x32 ----
  f32x4 acc2[2][4] = {};
#pragma unroll
  for (int kk = 0; kk < 4; ++kk) {
    const int pcsel = kk * 4 + l4;
    bf16x8 a2[2], bw[4];
#pragma unroll
    for (int m = 0; m < 2; ++m) {
      const int row = wave * 32 + m * 16 + l15;
      a2[m] = *(const bf16x8*)(smem + row * 256 + ((pcsel ^ (row & 15)) << 4));
    }
#pragma unroll
    for (int n = 0; n < 4; ++n) {
      const int rp = n * 16 + l15;
      bw[n] = *(const bf16x8*)(smem + 32768 + rp * 256 + ((pcsel ^ (rp & 15)) << 4));
    }
#pragma unroll
    for (int m = 0; m < 2; ++m)
#pragma unroll
      for (int n = 0; n < 4; ++n)
        acc2[m][n] = __builtin_amdgcn_mfma_f32_16x16x32_bf16(a2[m], bw[n], acc2[m][n], 0, 0, 0);
  }

  // ---- epilogue 3: L2 distance + log2-based activation ----
  float pb[4], pp[4];
#pragma unroll
  for (int n = 0; n < 4; ++n) {
    const int p = n * 16 + l15;
    pb[n] = b2[lat * NP + p];
    pp[n] = protos[lat * NP + p];
  }
  const float scale2 = 0.69314718056f * 300.0f / logf(10000.0f);
#pragma unroll
  for (int m = 0; m < 2; ++m)
#pragma unroll
    for (int r = 0; r < 4; ++r) {
      float s = 0.f;
#pragma unroll
      for (int n = 0; n < 4; ++n) {
        const float e = acc2[m][n][r] + pb[n] - pp[n];
        s += e * e;
      }
      s += __shfl_xor(s, 1);
      s += __shfl_xor(s, 2);
      s += __shfl_xor(s, 4);
      s += __shfl_xor(s, 8);
      if (l15 == 0) {
        const float a = (__log2f(s + 1.0f) - __log2f(s + 1e-4f)) * scale2 - 100.0f;
        const int trow = wave * 32 + m * 16 + l4 * 4 + r;
        out[(size_t)(t0 + trow) * NL + lat] = a;
      }
    }
}

extern "C" void kernel_launch(void* const* d_in, const int* in_sizes, int n_in,
                              void* d_out, int out_size, void* d_ws, size_t ws_size,
                              hipStream_t stream) {
  const float* x      = (const float*)d_in[0];
  const float* W1     = (const float*)d_in[1];
  const float* b1     = (const float*)d_in[2];
  const float* gamma  = (const float*)d_in[3];
  const float* beta   = (const float*)d_in[4];
  const float* rmean  = (const float*)d_in[5];
  const float* rvar   = (const float*)d_in[6];
  const float* W2     = (const float*)d_in[7];
  const float* b2     = (const float*)d_in[8];
  const float* protos = (const float*)d_in[9];
  float* out = (float*)d_out;

  // workspace: xq 8MB | w1q 16MB | w2b 2MB | sx 32KB | sw 64KB
  char* ws = (char*)d_ws;
  signed char*    xq  = (signed char*)ws;
  signed char*    w1q = (signed char*)(ws + (size_t)8 * 1024 * 1024);
  unsigned short* w2b = (unsigned short*)(ws + (size_t)24 * 1024 * 1024);
  float*          sx  = (float*)(ws + (size_t)26 * 1024 * 1024);
  float*          sw  = (float*)(ws + (size_t)26 * 1024 * 1024 + 64 * 1024);

  quant_rows_i8_dual<<<(NTOK + NL * NH) / 4, 256, 0, stream>>>(x, W1, xq, w1q, sx, sw);
  {
    const int n8w2 = NL * NP * NH / 8;
    cvt_f32_bf16<<<(n8w2 + 255) / 256, 256, 0, stream>>>(W2, w2b, n8w2);
  }

  dim3 grid(NTOK / 128, NL);
  proto_fused<<<grid, 256, 0, stream>>>(xq, w1q, w2b, sx, sw, b1, gamma, beta,
                                        rmean, rvar, b2, protos, out);
}

// Round 12
// 217.441 us; speedup vs baseline: 1.4089x; 1.0263x over previous
//
#include <hip/hip_runtime.h>

// ProtoSAE fused: h = relu(BN(x@W1^T + b1)); enc = h@W2^T + b2; act = f(||enc-proto||^2)
// T=8192, NI=1024, L=128, H=128, P=64.
// R12 (final, fixed): R6 proto_fused verbatim (best measured: 211us, 0 conflicts,
//      3 blocks/CU). Merged prepass with CORRECT W2-cvt block count (512, was 64
//      in R11 -> 7/8 of w2b stale -> absmax 119.75).

#define NTOK 8192
#define NI   1024
#define NL   128
#define NH   128
#define NP   64

typedef __bf16 bf16x8 __attribute__((ext_vector_type(8)));
typedef float f32x4 __attribute__((ext_vector_type(4)));
typedef int   i32x4 __attribute__((ext_vector_type(4)));

static __device__ __forceinline__ unsigned short f2bf(float f) {
  union { float f; unsigned int u; } v; v.f = f;
  const unsigned int u = v.u;
  return (unsigned short)((u + 0x7fffu + ((u >> 16) & 1u)) >> 16);  // RNE
}

// Merged prepass: blocks [0, 6144) quantize x (rows<NTOK) / W1 rows (1 wave per row);
// blocks [6144, 6144+512) convert W2 f32->bf16 (8 elems/thread, 131072 units total).
#define QBLOCKS 6144   // (NTOK + NL*NH) / 4
#define W2BLOCKS 512   // (NL*NP*NH/8 + 255) / 256
__global__ void prepass_all(const float* __restrict__ x,
                            const float* __restrict__ w1,
                            const float* __restrict__ w2,
                            signed char* __restrict__ xq,
                            signed char* __restrict__ w1q,
                            unsigned short* __restrict__ w2b,
                            float* __restrict__ sx,
                            float* __restrict__ sw) {
  if (blockIdx.x >= QBLOCKS) {
    const int i = (blockIdx.x - QBLOCKS) * 256 + threadIdx.x;  // < 131072
    const float4* p = (const float4*)w2;
    const float4 a = p[2 * i], b = p[2 * i + 1];
    unsigned short v[8] __attribute__((aligned(16))) = {
        f2bf(a.x), f2bf(a.y), f2bf(a.z), f2bf(a.w),
        f2bf(b.x), f2bf(b.y), f2bf(b.z), f2bf(b.w)};
    ((uint4*)w2b)[i] = *(const uint4*)v;
    return;
  }
  const int row = blockIdx.x * 4 + (threadIdx.x >> 6);
  const int lane = threadIdx.x & 63;
  const float* src;
  unsigned int* dst;
  float* sp;
  if (row < NTOK) {
    src = x + (size_t)row * 1024;
    dst = (unsigned int*)(xq + (size_t)row * 1024);
    sp  = sx + row;
  } else {
    const int r = row - NTOK;
    src = w1 + (size_t)r * 1024;
    dst = (unsigned int*)(w1q + (size_t)r * 1024);
    sp  = sw + r;
  }
  const float4* s4 = (const float4*)src;
  float4 v[4];
  float m = 0.f;
#pragma unroll
  for (int j = 0; j < 4; ++j) {
    v[j] = s4[lane + 64 * j];
    m = fmaxf(m, fmaxf(fmaxf(fabsf(v[j].x), fabsf(v[j].y)),
                       fmaxf(fabsf(v[j].z), fabsf(v[j].w))));
  }
#pragma unroll
  for (int s = 1; s < 64; s <<= 1) m = fmaxf(m, __shfl_xor(m, s));
  m = fmaxf(m, 1e-20f);
  const float inv = 127.0f / m;
  if (lane == 0) *sp = m * (1.0f / 127.0f);
#pragma unroll
  for (int j = 0; j < 4; ++j) {
    const int a = (int)rintf(fminf(127.f, fmaxf(-127.f, v[j].x * inv)));
    const int b = (int)rintf(fminf(127.f, fmaxf(-127.f, v[j].y * inv)));
    const int c = (int)rintf(fminf(127.f, fmaxf(-127.f, v[j].z * inv)));
    const int d = (int)rintf(fminf(127.f, fmaxf(-127.f, v[j].w * inv)));
    dst[lane + 64 * j] = (unsigned)(a & 255) | ((unsigned)(b & 255) << 8) |
                         ((unsigned)(c & 255) << 16) | ((unsigned)(d & 255) << 24);
  }
}

static __device__ __forceinline__ void async16(const void* g, void* l) {
  __builtin_amdgcn_global_load_lds(
      (const __attribute__((address_space(1))) unsigned int*)g,
      (__attribute__((address_space(3))) unsigned int*)l, 16, 0, 0);
}

// Block: 128 tokens x 1 latent, 4 waves as 2x2 (token-half x hcol-half).
// LDS: A [0,16K) 128x128 i8 swz(r&7); B [16K,32K) same; W2s [32K,48K) 64x128 bf16
//      swz(r&15) persistent; epilogue hs [0,32K) 128x128 bf16 swz(r&15).
__global__ __launch_bounds__(256, 3) void proto_fused(
    const signed char* __restrict__ xq,       // [8192][1024] i8
    const signed char* __restrict__ w1q,      // [16384][1024] i8
    const unsigned short* __restrict__ w2b,   // [128][64][128] bf16
    const float* __restrict__ sx,             // [8192]
    const float* __restrict__ sw,             // [16384]
    const float* __restrict__ b1,
    const float* __restrict__ gamma, const float* __restrict__ beta,
    const float* __restrict__ rmean, const float* __restrict__ rvar,
    const float* __restrict__ b2,
    const float* __restrict__ protos,
    float* __restrict__ out)                  // [8192][128]
{
  __shared__ __attribute__((aligned(128))) char smem[49152];
  const int tid  = threadIdx.x;
  const int wave = tid >> 6;
  const int lane = tid & 63;
  const int l15  = lane & 15;
  const int l4   = lane >> 4;
  const int wr   = wave >> 1;
  const int wc   = wave & 1;
  const int t0   = blockIdx.x * 128;
  const int lat  = blockIdx.y;

  const int srow  = lane >> 3;                    // row within 8-row staging chunk
  const int scolb = ((lane & 7) ^ srow) * 16;     // swizzled source byte offset

  i32x4 acc[4][4] = {};

  // ---- stage W2[lat] once: 64x128 bf16 -> smem+32768, chunk ^= row&15 swizzle ----
#pragma unroll
  for (int i = 0; i < 4; ++i) {
    const int r = wave * 4 + i * 16 + l4;              // 0..63
    const int c = (lane & 15) ^ (r & 15);
    async16(w2b + (size_t)lat * NP * NH + r * NH + c * 8,
            smem + 32768 + (wave * 64 + i * 256) * 16);
  }

  auto stage = [&](int ks) {
    const int k0 = ks * 128;
#pragma unroll
    for (int j = 0; j < 4; ++j) {
      const int row = wave * 32 + j * 8 + srow;
      async16(xq + (size_t)(t0 + row) * NI + k0 + scolb,
              smem + (wave * 4 + j) * 1024);
      async16(w1q + (size_t)(lat * NH + row) * NI + k0 + scolb,
              smem + 16384 + (wave * 4 + j) * 1024);
    }
  };

  // ---- GEMM1 main loop: i8 16x16x64, BK=128, 8 K-steps (m97 structure) ----
  stage(0);
  const int rx = l15 & 7;
  for (int ks = 0; ks < 8; ++ks) {
    __syncthreads();
#pragma unroll
    for (int kk = 0; kk < 2; ++kk) {
      const int koff = ((kk * 4 + l4) ^ rx) << 4;
      i32x4 a[4], b[4];
#pragma unroll
      for (int m = 0; m < 4; ++m)
        a[m] = *(const i32x4*)(smem + (wr * 64 + m * 16 + l15) * 128 + koff);
#pragma unroll
      for (int n = 0; n < 4; ++n)
        b[n] = *(const i32x4*)(smem + 16384 + (wc * 64 + n * 16 + l15) * 128 + koff);
#pragma unroll
      for (int m = 0; m < 4; ++m)
#pragma unroll
        for (int n = 0; n < 4; ++n)
          acc[m][n] = __builtin_amdgcn_mfma_i32_16x16x64_i8(a[m], b[n], acc[m][n], 0, 0, 0);
    }
    __syncthreads();
    if (ks + 1 < 8) stage(ks + 1);
  }

  // ---- epilogue 1: dequant + BN(eval) + ReLU -> hs bf16 [128][128] swz(r&15) ----
  float sxv[4][4];
#pragma unroll
  for (int m = 0; m < 4; ++m)
#pragma unroll
    for (int r = 0; r < 4; ++r)
      sxv[m][r] = sx[t0 + wr * 64 + m * 16 + l4 * 4 + r];

#pragma unroll
  for (int n = 0; n < 4; ++n) {
    const int hc = wc * 64 + n * 16 + l15;
    const int gi = lat * NH + hc;
    const float sc_ = gamma[gi] * rsqrtf(rvar[gi] + 1e-5f);
    const float Kc  = sw[gi] * sc_;
    const float Cc  = b1[gi] * sc_ + beta[gi] - rmean[gi] * sc_;
    const int cchunk = hc >> 3, cin = (hc & 7) * 2;
#pragma unroll
    for (int m = 0; m < 4; ++m)
#pragma unroll
      for (int r = 0; r < 4; ++r) {
        float v = fmaf((float)acc[m][n][r] * sxv[m][r], Kc, Cc);
        v = v > 0.f ? v : 0.f;
        const int row = wr * 64 + m * 16 + l4 * 4 + r;
        const int pbyte = row * 256 + ((cchunk ^ (l4 * 4 + r)) << 4) + cin;
        *(__bf16*)(smem + pbyte) = (__bf16)v;     // native HW cvt
      }
  }
  __syncthreads();   // drains W2 vmcnt + hs lgkm

  // ---- epilogue 2: enc = h @ W2^T (M=128, N=64, K=128), bf16, swizzled reads ----
  f32x4 acc2[2][4] = {};
#pragma unroll
  for (int kk = 0; kk < 4; ++kk) {
    const int pcsel = kk * 4 + l4;
    bf16x8 a2[2], bw[4];
#pragma unroll
    for (int m = 0; m < 2; ++m) {
      const int row = wave * 32 + m * 16 + l15;
      a2[m] = *(const bf16x8*)(smem + row * 256 + ((pcsel ^ (row & 15)) << 4));
    }
#pragma unroll
    for (int n = 0; n < 4; ++n) {
      const int rp = n * 16 + l15;
      bw[n] = *(const bf16x8*)(smem + 32768 + rp * 256 + ((pcsel ^ (rp & 15)) << 4));
    }
#pragma unroll
    for (int m = 0; m < 2; ++m)
#pragma unroll
      for (int n = 0; n < 4; ++n)
        acc2[m][n] = __builtin_amdgcn_mfma_f32_16x16x32_bf16(a2[m], bw[n], acc2[m][n], 0, 0, 0);
  }

  // ---- epilogue 3: L2 distance + log2-based activation ----
  float pd[4];
#pragma unroll
  for (int n = 0; n < 4; ++n) {
    const int p = n * 16 + l15;
    pd[n] = b2[lat * NP + p] - protos[lat * NP + p];   // folded bias - prototype
  }
  const float scale2 = 0.69314718056f * 300.0f / logf(10000.0f);
#pragma unroll
  for (int m = 0; m < 2; ++m)
#pragma unroll
    for (int r = 0; r < 4; ++r) {
      float s = 0.f;
#pragma unroll
      for (int n = 0; n < 4; ++n) {
        const float e = acc2[m][n][r] + pd[n];
        s += e * e;
      }
      s += __shfl_xor(s, 1);
      s += __shfl_xor(s, 2);
      s += __shfl_xor(s, 4);
      s += __shfl_xor(s, 8);
      if (l15 == 0) {
        const float a = (__log2f(s + 1.0f) - __log2f(s + 1e-4f)) * scale2 - 100.0f;
        const int trow = wave * 32 + m * 16 + l4 * 4 + r;
        out[(size_t)(t0 + trow) * NL + lat] = a;
      }
    }
}

extern "C" void kernel_launch(void* const* d_in, const int* in_sizes, int n_in,
                              void* d_out, int out_size, void* d_ws, size_t ws_size,
                              hipStream_t stream) {
  const float* x      = (const float*)d_in[0];
  const float* W1     = (const float*)d_in[1];
  const float* b1     = (const float*)d_in[2];
  const float* gamma  = (const float*)d_in[3];
  const float* beta   = (const float*)d_in[4];
  const float* rmean  = (const float*)d_in[5];
  const float* rvar   = (const float*)d_in[6];
  const float* W2     = (const float*)d_in[7];
  const float* b2     = (const float*)d_in[8];
  const float* protos = (const float*)d_in[9];
  float* out = (float*)d_out;

  // workspace: xq 8MB | w1q 16MB | w2b 2MB | sx 32KB | sw 64KB
  char* ws = (char*)d_ws;
  signed char*    xq  = (signed char*)ws;
  signed char*    w1q = (signed char*)(ws + (size_t)8 * 1024 * 1024);
  unsigned short* w2b = (unsigned short*)(ws + (size_t)24 * 1024 * 1024);
  float*          sx  = (float*)(ws + (size_t)26 * 1024 * 1024);
  float*          sw  = (float*)(ws + (size_t)26 * 1024 * 1024 + 64 * 1024);

  // one merged prepass: 6144 quant blocks + 512 W2-cvt blocks
  prepass_all<<<QBLOCKS + W2BLOCKS, 256, 0, stream>>>(x, W1, W2, xq, w1q, w2b, sx, sw);

  dim3 grid(NTOK / 128, NL);
  proto_fused<<<grid, 256, 0, stream>>>(xq, w1q, w2b, sx, sw, b1, gamma, beta,
                                        rmean, rvar, b2, protos, out);
}

// Round 13
// 211.044 us; speedup vs baseline: 1.4517x; 1.0303x over previous
//
#include <hip/hip_runtime.h>

// ProtoSAE fused: h = relu(BN(x@W1^T + b1)); enc = h@W2^T + b2; act = f(||enc-proto||^2)
// T=8192, NI=1024, L=128, H=128, P=64.
// R13: R12 (best: proto 211us, 0 conflicts, 3 blocks/CU) + XCD-chunked block swizzle
//      isolated (R7 measured FETCH 113->72MB with it; here without R7's harmful
//      W2-from-global change). Everything else bit-identical to R12.

#define NTOK 8192
#define NI   1024
#define NL   128
#define NH   128
#define NP   64

typedef __bf16 bf16x8 __attribute__((ext_vector_type(8)));
typedef float f32x4 __attribute__((ext_vector_type(4)));
typedef int   i32x4 __attribute__((ext_vector_type(4)));

static __device__ __forceinline__ unsigned short f2bf(float f) {
  union { float f; unsigned int u; } v; v.f = f;
  const unsigned int u = v.u;
  return (unsigned short)((u + 0x7fffu + ((u >> 16) & 1u)) >> 16);  // RNE
}

// Merged prepass: blocks [0, 6144) quantize x (rows<NTOK) / W1 rows (1 wave per row);
// blocks [6144, 6144+512) convert W2 f32->bf16 (8 elems/thread, 131072 units total).
#define QBLOCKS 6144   // (NTOK + NL*NH) / 4
#define W2BLOCKS 512   // NL*NP*NH/8 / 256
__global__ void prepass_all(const float* __restrict__ x,
                            const float* __restrict__ w1,
                            const float* __restrict__ w2,
                            signed char* __restrict__ xq,
                            signed char* __restrict__ w1q,
                            unsigned short* __restrict__ w2b,
                            float* __restrict__ sx,
                            float* __restrict__ sw) {
  if (blockIdx.x >= QBLOCKS) {
    const int i = (blockIdx.x - QBLOCKS) * 256 + threadIdx.x;  // < 131072
    const float4* p = (const float4*)w2;
    const float4 a = p[2 * i], b = p[2 * i + 1];
    unsigned short v[8] __attribute__((aligned(16))) = {
        f2bf(a.x), f2bf(a.y), f2bf(a.z), f2bf(a.w),
        f2bf(b.x), f2bf(b.y), f2bf(b.z), f2bf(b.w)};
    ((uint4*)w2b)[i] = *(const uint4*)v;
    return;
  }
  const int row = blockIdx.x * 4 + (threadIdx.x >> 6);
  const int lane = threadIdx.x & 63;
  const float* src;
  unsigned int* dst;
  float* sp;
  if (row < NTOK) {
    src = x + (size_t)row * 1024;
    dst = (unsigned int*)(xq + (size_t)row * 1024);
    sp  = sx + row;
  } else {
    const int r = row - NTOK;
    src = w1 + (size_t)r * 1024;
    dst = (unsigned int*)(w1q + (size_t)r * 1024);
    sp  = sw + r;
  }
  const float4* s4 = (const float4*)src;
  float4 v[4];
  float m = 0.f;
#pragma unroll
  for (int j = 0; j < 4; ++j) {
    v[j] = s4[lane + 64 * j];
    m = fmaxf(m, fmaxf(fmaxf(fabsf(v[j].x), fabsf(v[j].y)),
                       fmaxf(fabsf(v[j].z), fabsf(v[j].w))));
  }
#pragma unroll
  for (int s = 1; s < 64; s <<= 1) m = fmaxf(m, __shfl_xor(m, s));
  m = fmaxf(m, 1e-20f);
  const float inv = 127.0f / m;
  if (lane == 0) *sp = m * (1.0f / 127.0f);
#pragma unroll
  for (int j = 0; j < 4; ++j) {
    const int a = (int)rintf(fminf(127.f, fmaxf(-127.f, v[j].x * inv)));
    const int b = (int)rintf(fminf(127.f, fmaxf(-127.f, v[j].y * inv)));
    const int c = (int)rintf(fminf(127.f, fmaxf(-127.f, v[j].z * inv)));
    const int d = (int)rintf(fminf(127.f, fmaxf(-127.f, v[j].w * inv)));
    dst[lane + 64 * j] = (unsigned)(a & 255) | ((unsigned)(b & 255) << 8) |
                         ((unsigned)(c & 255) << 16) | ((unsigned)(d & 255) << 24);
  }
}

static __device__ __forceinline__ void async16(const void* g, void* l) {
  __builtin_amdgcn_global_load_lds(
      (const __attribute__((address_space(1))) unsigned int*)g,
      (__attribute__((address_space(3))) unsigned int*)l, 16, 0, 0);
}

// Block: 128 tokens x 1 latent, 4 waves as 2x2 (token-half x hcol-half).
// LDS: A [0,16K) 128x128 i8 swz(r&7); B [16K,32K) same; W2s [32K,48K) 64x128 bf16
//      swz(r&15) persistent; epilogue hs [0,32K) 128x128 bf16 swz(r&15).
__global__ __launch_bounds__(256, 3) void proto_fused(
    const signed char* __restrict__ xq,       // [8192][1024] i8
    const signed char* __restrict__ w1q,      // [16384][1024] i8
    const unsigned short* __restrict__ w2b,   // [128][64][128] bf16
    const float* __restrict__ sx,             // [8192]
    const float* __restrict__ sw,             // [16384]
    const float* __restrict__ b1,
    const float* __restrict__ gamma, const float* __restrict__ beta,
    const float* __restrict__ rmean, const float* __restrict__ rvar,
    const float* __restrict__ b2,
    const float* __restrict__ protos,
    float* __restrict__ out)                  // [8192][128]
{
  __shared__ __attribute__((aligned(128))) char smem[49152];
  const int tid  = threadIdx.x;
  const int wave = tid >> 6;
  const int lane = tid & 63;
  const int l15  = lane & 15;
  const int l4   = lane >> 4;
  const int wr   = wave >> 1;
  const int wc   = wave & 1;

  // XCD-chunked swizzle (T1, R7-proven bijection): id&7 = XCD; each XCD owns 16
  // latents x all 64 token-tiles, walked in (8 tt x 16 lat) chunks. Working set
  // per chunk = W1 band 2MB (persists across chunks) + x tiles 1MB < 4MB L2.
  const int id    = blockIdx.x;
  const int xcd   = id & 7;
  const int local = id >> 3;            // 0..1023
  const int chunk = local >> 7;         // 0..7
  const int wi    = local & 127;
  const int tt    = chunk * 8 + (wi & 7);
  const int lat   = xcd * 16 + (wi >> 3);
  const int t0    = tt * 128;

  const int srow  = lane >> 3;                    // row within 8-row staging chunk
  const int scolb = ((lane & 7) ^ srow) * 16;     // swizzled source byte offset

  i32x4 acc[4][4] = {};

  // ---- stage W2[lat] once: 64x128 bf16 -> smem+32768, chunk ^= row&15 swizzle ----
#pragma unroll
  for (int i = 0; i < 4; ++i) {
    const int r = wave * 4 + i * 16 + l4;              // 0..63
    const int c = (lane & 15) ^ (r & 15);
    async16(w2b + (size_t)lat * NP * NH + r * NH + c * 8,
            smem + 32768 + (wave * 64 + i * 256) * 16);
  }

  auto stage = [&](int ks) {
    const int k0 = ks * 128;
#pragma unroll
    for (int j = 0; j < 4; ++j) {
      const int row = wave * 32 + j * 8 + srow;
      async16(xq + (size_t)(t0 + row) * NI + k0 + scolb,
              smem + (wave * 4 + j) * 1024);
      async16(w1q + (size_t)(lat * NH + row) * NI + k0 + scolb,
              smem + 16384 + (wave * 4 + j) * 1024);
    }
  };

  // ---- GEMM1 main loop: i8 16x16x64, BK=128, 8 K-steps (m97 structure) ----
  stage(0);
  const int rx = l15 & 7;
  for (int ks = 0; ks < 8; ++ks) {
    __syncthreads();
#pragma unroll
    for (int kk = 0; kk < 2; ++kk) {
      const int koff = ((kk * 4 + l4) ^ rx) << 4;
      i32x4 a[4], b[4];
#pragma unroll
      for (int m = 0; m < 4; ++m)
        a[m] = *(const i32x4*)(smem + (wr * 64 + m * 16 + l15) * 128 + koff);
#pragma unroll
      for (int n = 0; n < 4; ++n)
        b[n] = *(const i32x4*)(smem + 16384 + (wc * 64 + n * 16 + l15) * 128 + koff);
#pragma unroll
      for (int m = 0; m < 4; ++m)
#pragma unroll
        for (int n = 0; n < 4; ++n)
          acc[m][n] = __builtin_amdgcn_mfma_i32_16x16x64_i8(a[m], b[n], acc[m][n], 0, 0, 0);
    }
    __syncthreads();
    if (ks + 1 < 8) stage(ks + 1);
  }

  // ---- epilogue 1: dequant + BN(eval) + ReLU -> hs bf16 [128][128] swz(r&15) ----
  float sxv[4][4];
#pragma unroll
  for (int m = 0; m < 4; ++m)
#pragma unroll
    for (int r = 0; r < 4; ++r)
      sxv[m][r] = sx[t0 + wr * 64 + m * 16 + l4 * 4 + r];

#pragma unroll
  for (int n = 0; n < 4; ++n) {
    const int hc = wc * 64 + n * 16 + l15;
    const int gi = lat * NH + hc;
    const float sc_ = gamma[gi] * rsqrtf(rvar[gi] + 1e-5f);
    const float Kc  = sw[gi] * sc_;
    const float Cc  = b1[gi] * sc_ + beta[gi] - rmean[gi] * sc_;
    const int cchunk = hc >> 3, cin = (hc & 7) * 2;
#pragma unroll
    for (int m = 0; m < 4; ++m)
#pragma unroll
      for (int r = 0; r < 4; ++r) {
        float v = fmaf((float)acc[m][n][r] * sxv[m][r], Kc, Cc);
        v = v > 0.f ? v : 0.f;
        const int row = wr * 64 + m * 16 + l4 * 4 + r;
        const int pbyte = row * 256 + ((cchunk ^ (l4 * 4 + r)) << 4) + cin;
        *(__bf16*)(smem + pbyte) = (__bf16)v;     // native HW cvt
      }
  }
  __syncthreads();   // drains W2 vmcnt + hs lgkm

  // ---- epilogue 2: enc = h @ W2^T (M=128, N=64, K=128), bf16, swizzled reads ----
  f32x4 acc2[2][4] = {};
#pragma unroll
  for (int kk = 0; kk < 4; ++kk) {
    const int pcsel = kk * 4 + l4;
    bf16x8 a2[2], bw[4];
#pragma unroll
    for (int m = 0; m < 2; ++m) {
      const int row = wave * 32 + m * 16 + l15;
      a2[m] = *(const bf16x8*)(smem + row * 256 + ((pcsel ^ (row & 15)) << 4));
    }
#pragma unroll
    for (int n = 0; n < 4; ++n) {
      const int rp = n * 16 + l15;
      bw[n] = *(const bf16x8*)(smem + 32768 + rp * 256 + ((pcsel ^ (rp & 15)) << 4));
    }
#pragma unroll
    for (int m = 0; m < 2; ++m)
#pragma unroll
      for (int n = 0; n < 4; ++n)
        acc2[m][n] = __builtin_amdgcn_mfma_f32_16x16x32_bf16(a2[m], bw[n], acc2[m][n], 0, 0, 0);
  }

  // ---- epilogue 3: L2 distance + log2-based activation ----
  float pd[4];
#pragma unroll
  for (int n = 0; n < 4; ++n) {
    const int p = n * 16 + l15;
    pd[n] = b2[lat * NP + p] - protos[lat * NP + p];   // folded bias - prototype
  }
  const float scale2 = 0.69314718056f * 300.0f / logf(10000.0f);
#pragma unroll
  for (int m = 0; m < 2; ++m)
#pragma unroll
    for (int r = 0; r < 4; ++r) {
      float s = 0.f;
#pragma unroll
      for (int n = 0; n < 4; ++n) {
        const float e = acc2[m][n][r] + pd[n];
        s += e * e;
      }
      s += __shfl_xor(s, 1);
      s += __shfl_xor(s, 2);
      s += __shfl_xor(s, 4);
      s += __shfl_xor(s, 8);
      if (l15 == 0) {
        const float a = (__log2f(s + 1.0f) - __log2f(s + 1e-4f)) * scale2 - 100.0f;
        const int trow = wave * 32 + m * 16 + l4 * 4 + r;
        out[(size_t)(t0 + trow) * NL + lat] = a;
      }
    }
}

extern "C" void kernel_launch(void* const* d_in, const int* in_sizes, int n_in,
                              void* d_out, int out_size, void* d_ws, size_t ws_size,
                              hipStream_t stream) {
  const float* x      = (const float*)d_in[0];
  const float* W1     = (const float*)d_in[1];
  const float* b1     = (const float*)d_in[2];
  const float* gamma  = (const float*)d_in[3];
  const float* beta   = (const float*)d_in[4];
  const float* rmean  = (const float*)d_in[5];
  const float* rvar   = (const float*)d_in[6];
  const float* W2     = (const float*)d_in[7];
  const float* b2     = (const float*)d_in[8];
  const float* protos = (const float*)d_in[9];
  float* out = (float*)d_out;

  // workspace: xq 8MB | w1q 16MB | w2b 2MB | sx 32KB | sw 64KB
  char* ws = (char*)d_ws;
  signed char*    xq  = (signed char*)ws;
  signed char*    w1q = (signed char*)(ws + (size_t)8 * 1024 * 1024);
  unsigned short* w2b = (unsigned short*)(ws + (size_t)24 * 1024 * 1024);
  float*          sx  = (float*)(ws + (size_t)26 * 1024 * 1024);
  float*          sw  = (float*)(ws + (size_t)26 * 1024 * 1024 + 64 * 1024);

  // one merged prepass: 6144 quant blocks + 512 W2-cvt blocks
  prepass_all<<<QBLOCKS + W2BLOCKS, 256, 0, stream>>>(x, W1, W2, xq, w1q, w2b, sx, sw);

  proto_fused<<<dim3(8192), 256, 0, stream>>>(xq, w1q, w2b, sx, sw, b1, gamma, beta,
                                              rmean, rvar, b2, protos, out);
}